// Round 7
// baseline (20.764 us; speedup 1.0000x reference)
//
#include <hip/hip_runtime.h>

#define T_LEN 16384
#define B_N   128
#define S_N   31
#define M_SH  15
#define NCHUNK 8
#define TCHUNK (T_LEN / NCHUNK)   // 2048
#define BLOCK  256
#define VT     8
#define NBLOCKS (B_N * NCHUNK)    // 1024
#define HALO   16
#define TILE_F4 ((TCHUNK + 2 * HALO) / 4)   // 520

// XOR swizzle at float4 granularity: spreads the 32B-strided window reads
// across banks (worst case 2-way = free). Bijective within 128B groups.
__device__ __forceinline__ int swz(int f4) { return f4 ^ ((f4 >> 3) & 7); }

__global__ __launch_bounds__(BLOCK) void talos_fused(
    const float* __restrict__ y_pred,
    const float* __restrict__ y_true,
    const float* __restrict__ theta,
    const int* __restrict__ pidx,
    float* __restrict__ partial,
    unsigned int* __restrict__ ticket,
    float* __restrict__ out) {

  __shared__ float tile[TILE_F4 * 4];          // 8320 B, swizzled
  __shared__ float wsh[S_N];
  __shared__ float redL[BLOCK / 64];
  __shared__ int   is_last;

  const int bid   = blockIdx.x;
  const int b     = bid / NCHUNK;
  const int chunk = bid % NCHUNK;
  const int t0    = chunk * TCHUNK;
  const int tid   = threadIdx.x;
  const float* yt_b = y_true + b * T_LEN;
  const float* yp_b = y_pred + b * T_LEN;

  // ---- issue theta load FIRST so its latency hides under tile staging ----
  float thv = -1e30f;
  if (tid < S_N) thv = theta[pidx[b] * S_N + tid];

  // ---- stage y_true chunk + halo into swizzled LDS (float4, zero-padded) ----
  for (int f = tid; f < TILE_F4; f += BLOCK) {
    int g = t0 - HALO + f * 4;                 // 16B-aligned global float index
    float4 v;
    if (g >= 0 && g + 3 < T_LEN) {
      v = *(const float4*)(yt_b + g);
    } else {
      v.x = (g + 0 >= 0 && g + 0 < T_LEN) ? yt_b[g + 0] : 0.f;
      v.y = (g + 1 >= 0 && g + 1 < T_LEN) ? yt_b[g + 1] : 0.f;
      v.z = (g + 2 >= 0 && g + 2 < T_LEN) ? yt_b[g + 2] : 0.f;
      v.w = (g + 3 >= 0 && g + 3 < T_LEN) ? yt_b[g + 3] : 0.f;
    }
    *(float4*)&tile[swz(f) * 4] = v;
  }

  // ---- yp loads issued before the barrier (independent of LDS) ----
  const int lt0 = tid * VT;
  float yp[VT];
  *(float4*)&yp[0] = *(const float4*)(yp_b + t0 + lt0);
  *(float4*)&yp[4] = *(const float4*)(yp_b + t0 + lt0 + 4);

  // ---- softmax weights for this b (wave 0, lanes 0..31) ----
  if (tid < 32) {
    float m = thv;
#pragma unroll
    for (int off = 16; off; off >>= 1) m = fmaxf(m, __shfl_xor(m, off, 32));
    float e = (tid < S_N) ? __expf(thv - m) : 0.f;
    float s = e;
#pragma unroll
    for (int off = 16; off; off >>= 1) s += __shfl_xor(s, off, 32);
    if (tid < S_N) wsh[tid] = e / s;
  }
  __syncthreads();

  // ---- register-blocked weighted 31-tap convolution over VT=8 elements ----
  float win[VT + 2 * HALO];                    // 40 floats: yt[t0+lt0-16 .. +23]
#pragma unroll
  for (int q = 0; q < (VT + 2 * HALO) / 4; ++q) {
    int f4 = (lt0 >> 2) + q;                   // 2*tid + q
    *(float4*)&win[q * 4] = *(const float4*)&tile[swz(f4) * 4];
  }

  float lin[VT];
#pragma unroll
  for (int j = 0; j < VT; ++j) lin[j] = 0.f;
#pragma unroll
  for (int s = 0; s < S_N; ++s) {
    const float ws = wsh[s];                   // LDS broadcast (no conflict)
#pragma unroll
    for (int j = 0; j < VT; ++j)
      lin[j] = fmaf(ws, win[j + s + 1], lin[j]);   // lin[t] = sum_s w_s*yt[t+s-15]
  }

  // acc = sum (yp^2 - 2*yp*lin) + sum yt^2   (weighted yt^2 collapses to the
  // unweighted per-chunk sum since sum_s w_s = 1; edges corrected below)
  float acc = 0.f;
#pragma unroll
  for (int j = 0; j < VT; ++j) {
    acc = fmaf(yp[j], fmaf(-2.f, lin[j], yp[j]), acc);
    float a = win[HALO + j];
    acc = fmaf(a, a, acc);
  }

  // ---- zero-pad edge corrections, wave-parallel (verified absmax=0, R4-R6) ----
  if (chunk == 0 && tid < M_SH) {
    float a = yt_b[tid];
    float tw = 0.f;
#pragma unroll
    for (int k = 1; k <= M_SH; ++k) if (k > tid) tw += wsh[k + M_SH];
    acc -= a * a * tw;
  }
  if (chunk == NCHUNK - 1 && tid < M_SH) {
    const int j = tid + 1;
    float z = yt_b[T_LEN - j];
    float tw = 0.f;
#pragma unroll
    for (int k = 1; k <= M_SH; ++k) if (k >= j) tw += wsh[M_SH - k];
    acc -= z * z * tw;
  }

  // ---- block reduce -> partial[bid] ----
#pragma unroll
  for (int off = 32; off; off >>= 1) acc += __shfl_down(acc, off, 64);
  const int lane = tid & 63, wv = tid >> 6;
  if (lane == 0) redL[wv] = acc;
  __syncthreads();

  if (tid == 0) {
    float P = 0.f;
#pragma unroll
    for (int i = 0; i < BLOCK / 64; ++i) P += redL[i];
    // RELAXED agent store: write-through (sc1) to device coherent point —
    // no buffer_wbl2 cache flush (that was R5's 25us mistake: RELEASE).
    __hip_atomic_store(&partial[bid], P, __ATOMIC_RELAXED,
                       __HIP_MEMORY_SCOPE_AGENT);
    // Ack: vmcnt(0) means the store reached global visibility.
    asm volatile("s_waitcnt vmcnt(0)" ::: "memory");
    // Relaxed device-scope ticket (atomics execute at the coherent point).
    unsigned int t = __hip_atomic_fetch_add(ticket, 1u, __ATOMIC_RELAXED,
                                            __HIP_MEMORY_SCOPE_AGENT);
    // Modulo trick: any 1024 consecutive tickets contain exactly one value
    // == 1023 (mod 1024) -> no reset/memset needed across graph replays.
    is_last = (((t + 1u) & (unsigned)(NBLOCKS - 1)) == 0u);
  }
  __syncthreads();

  // ---- last-arriving block: fixed-order final reduction (deterministic) ----
  if (is_last) {
    double a = 0.0;
    for (int i = tid; i < NBLOCKS; i += BLOCK)
      a += (double)__hip_atomic_load(&partial[i], __ATOMIC_RELAXED,
                                     __HIP_MEMORY_SCOPE_AGENT);
#pragma unroll
    for (int off = 32; off; off >>= 1) a += __shfl_down(a, off, 64);
    __shared__ double redD[BLOCK / 64];
    if (lane == 0) redD[wv] = a;
    __syncthreads();
    if (tid == 0) {
      double tot = 0.0;
#pragma unroll
      for (int i = 0; i < BLOCK / 64; ++i) tot += redD[i];
      out[0] = (float)(tot / ((double)T_LEN * (double)B_N));
    }
  }
}

extern "C" void kernel_launch(void* const* d_in, const int* in_sizes, int n_in,
                              void* d_out, int out_size, void* d_ws, size_t ws_size,
                              hipStream_t stream) {
  const float* y_pred = (const float*)d_in[0];
  const float* y_true = (const float*)d_in[1];
  const float* theta  = (const float*)d_in[2];
  const int*   pidx   = (const int*)d_in[3];
  float* out = (float*)d_out;

  float*        partial = (float*)d_ws;                     // 1024 floats
  unsigned int* ticket  = (unsigned int*)((char*)d_ws + 4096);

  talos_fused<<<NBLOCKS, BLOCK, 0, stream>>>(y_pred, y_true, theta, pidx,
                                             partial, ticket, out);
}

// Round 9
// 11.524 us; speedup vs baseline: 1.8019x; 1.8019x over previous
//
#include <hip/hip_runtime.h>

#define T_LEN 16384
#define B_N   128
#define S_N   31
#define M_SH  15
#define NCHUNK 8
#define TCHUNK (T_LEN / NCHUNK)   // 2048
#define BLOCK  256
#define VT     8
#define NBLOCKS (B_N * NCHUNK)    // 1024 = 4 blocks/CU
#define HALO   16
#define TILE_F4 ((TCHUNK + 2 * HALO) / 4)   // 520

typedef float fx4 __attribute__((ext_vector_type(4)));   // native vector: OK for nontemporal builtins

// XOR swizzle at float4 granularity: spreads the 32B-strided window reads
// across banks (worst case 2-way = free). Bijective within 128B groups.
__device__ __forceinline__ int swz(int f4) { return f4 ^ ((f4 >> 3) & 7); }

__device__ __forceinline__ fx4 ntload4(const float* p) {
  return __builtin_nontemporal_load((const fx4*)p);
}

// __launch_bounds__(256,4): <=128 VGPR -> 4 blocks/CU co-resident (16 waves/CU).
__global__ __launch_bounds__(BLOCK, 4) void talos_main(
    const float* __restrict__ y_pred,
    const float* __restrict__ y_true,
    const float* __restrict__ theta,
    const int* __restrict__ pidx,
    float* __restrict__ partial) {

  __shared__ float tile[TILE_F4 * 4];          // 8320 B, swizzled
  __shared__ float wsh[S_N];
  __shared__ float redL[BLOCK / 64];

  const int bid   = blockIdx.x;
  const int b     = bid / NCHUNK;
  const int chunk = bid % NCHUNK;
  const int t0    = chunk * TCHUNK;
  const int tid   = threadIdx.x;
  const float* yt_b = y_true + b * T_LEN;
  const float* yp_b = y_pred + b * T_LEN;

  // ---- issue theta load first: latency hides under tile staging ----
  float thv = -1e30f;
  if (tid < S_N) thv = theta[pidx[b] * S_N + tid];

  // ---- yp loads issued early (independent of LDS); nontemporal: no reuse ----
  const int lt0 = tid * VT;
  float yp[VT];
  *(fx4*)&yp[0] = ntload4(yp_b + t0 + lt0);
  *(fx4*)&yp[4] = ntload4(yp_b + t0 + lt0 + 4);

  // ---- stage y_true chunk + halo into swizzled LDS (float4, zero-padded) ----
  // y_true has no intra-block L1 reuse (halo reuse is cross-block via L2):
  // nontemporal keeps L1 clean. Two full passes + 8-thread remainder.
  {
    int f = tid;                               // pass 0: f in [0,256)
    int g = t0 - HALO + f * 4;
    fx4 v;
    if (g >= 0 && g + 3 < T_LEN) {
      v = ntload4(yt_b + g);
    } else {
      v.x = (g + 0 >= 0 && g + 0 < T_LEN) ? yt_b[g + 0] : 0.f;
      v.y = (g + 1 >= 0 && g + 1 < T_LEN) ? yt_b[g + 1] : 0.f;
      v.z = (g + 2 >= 0 && g + 2 < T_LEN) ? yt_b[g + 2] : 0.f;
      v.w = (g + 3 >= 0 && g + 3 < T_LEN) ? yt_b[g + 3] : 0.f;
    }
    *(fx4*)&tile[swz(f) * 4] = v;

    f = tid + BLOCK;                           // pass 1: f in [256,512)
    g = t0 - HALO + f * 4;
    v = ntload4(yt_b + g);                     // always interior of the row
    *(fx4*)&tile[swz(f) * 4] = v;

    if (tid < TILE_F4 - 2 * BLOCK) {           // remainder: f in [512,520)
      f = tid + 2 * BLOCK;
      g = t0 - HALO + f * 4;
      if (g + 3 < T_LEN) {
        v = ntload4(yt_b + g);
      } else {
        v.x = (g + 0 < T_LEN) ? yt_b[g + 0] : 0.f;
        v.y = (g + 1 < T_LEN) ? yt_b[g + 1] : 0.f;
        v.z = (g + 2 < T_LEN) ? yt_b[g + 2] : 0.f;
        v.w = (g + 3 < T_LEN) ? yt_b[g + 3] : 0.f;
      }
      *(fx4*)&tile[swz(f) * 4] = v;
    }
  }

  // ---- softmax weights for this b (wave 0, lanes 0..31) ----
  if (tid < 32) {
    float m = thv;
#pragma unroll
    for (int off = 16; off; off >>= 1) m = fmaxf(m, __shfl_xor(m, off, 32));
    float e = (tid < S_N) ? __expf(thv - m) : 0.f;
    float s = e;
#pragma unroll
    for (int off = 16; off; off >>= 1) s += __shfl_xor(s, off, 32);
    if (tid < S_N) wsh[tid] = e / s;
  }
  __syncthreads();

  // ---- register-blocked weighted 31-tap convolution over VT=8 elements ----
  float win[VT + 2 * HALO];                    // 40 floats: yt[t0+lt0-16 .. +23]
#pragma unroll
  for (int q = 0; q < (VT + 2 * HALO) / 4; ++q) {
    int f4 = (lt0 >> 2) + q;                   // 2*tid + q
    *(fx4*)&win[q * 4] = *(const fx4*)&tile[swz(f4) * 4];
  }

  float lin[VT];
#pragma unroll
  for (int j = 0; j < VT; ++j) lin[j] = 0.f;
#pragma unroll
  for (int s = 0; s < S_N; ++s) {
    const float ws = wsh[s];                   // LDS broadcast (no conflict)
#pragma unroll
    for (int j = 0; j < VT; ++j)
      lin[j] = fmaf(ws, win[j + s + 1], lin[j]);   // lin[t] = sum_s w_s*yt[t+s-15]
  }

  // acc = sum (yp^2 - 2*yp*lin) + sum yt^2   (weighted yt^2 collapses to the
  // unweighted per-chunk sum since sum_s w_s = 1; edges corrected below)
  float acc = 0.f;
#pragma unroll
  for (int j = 0; j < VT; ++j) {
    acc = fmaf(yp[j], fmaf(-2.f, lin[j], yp[j]), acc);
    float a = win[HALO + j];
    acc = fmaf(a, a, acc);
  }

  // ---- zero-pad edge corrections, wave-parallel (verified absmax=0, R4-R6) ----
  if (chunk == 0 && tid < M_SH) {
    float a = yt_b[tid];
    float tw = 0.f;
#pragma unroll
    for (int k = 1; k <= M_SH; ++k) if (k > tid) tw += wsh[k + M_SH];
    acc -= a * a * tw;
  }
  if (chunk == NCHUNK - 1 && tid < M_SH) {
    const int j = tid + 1;
    float z = yt_b[T_LEN - j];
    float tw = 0.f;
#pragma unroll
    for (int k = 1; k <= M_SH; ++k) if (k >= j) tw += wsh[M_SH - k];
    acc -= z * z * tw;
  }

  // ---- block reduce -> partial[bid] (plain store; kernel boundary = release) ----
#pragma unroll
  for (int off = 32; off; off >>= 1) acc += __shfl_down(acc, off, 64);
  const int lane = tid & 63, wv = tid >> 6;
  if (lane == 0) redL[wv] = acc;
  __syncthreads();
  if (tid == 0) {
    float P = 0.f;
#pragma unroll
    for (int i = 0; i < BLOCK / 64; ++i) P += redL[i];
    partial[bid] = P;
  }
}

// Minimal tail: ONE wave (64 threads), 16 partials/thread as 4x float4,
// in-register + shuffle reduce only — no LDS, no __syncthreads.
__global__ __launch_bounds__(64) void talos_tail(
    const float* __restrict__ partial, float* __restrict__ out) {
  const int tid = threadIdx.x;                 // 0..63
  double a = 0.0;
#pragma unroll
  for (int q = 0; q < 4; ++q) {
    fx4 v = *(const fx4*)(partial + (q * 64 + tid) * 4);
    a += (double)v.x + (double)v.y + (double)v.z + (double)v.w;
  }
#pragma unroll
  for (int off = 32; off; off >>= 1) a += __shfl_down(a, off, 64);
  if (tid == 0)
    out[0] = (float)(a / ((double)T_LEN * (double)B_N));
}

extern "C" void kernel_launch(void* const* d_in, const int* in_sizes, int n_in,
                              void* d_out, int out_size, void* d_ws, size_t ws_size,
                              hipStream_t stream) {
  const float* y_pred = (const float*)d_in[0];
  const float* y_true = (const float*)d_in[1];
  const float* theta  = (const float*)d_in[2];
  const int*   pidx   = (const int*)d_in[3];
  float* out = (float*)d_out;
  float* partial = (float*)d_ws;               // 1024 floats

  talos_main<<<NBLOCKS, BLOCK, 0, stream>>>(y_pred, y_true, theta, pidx, partial);
  talos_tail<<<1, 64, 0, stream>>>(partial, out);
}

// Round 10
// 11.446 us; speedup vs baseline: 1.8141x; 1.0068x over previous
//
#include <hip/hip_runtime.h>

#define T_LEN 16384
#define B_N   128
#define S_N   31
#define M_SH  15
#define NCHUNK 16
#define TCHUNK (T_LEN / NCHUNK)   // 1024
#define BLOCK  128
#define VT     8
#define NBLOCKS (B_N * NCHUNK)    // 2048 = 8 blocks/CU (2 waves each)
#define HALO   16
#define TILE_F4 ((TCHUNK + 2 * HALO) / 4)   // 264

typedef float fx4 __attribute__((ext_vector_type(4)));

// XOR swizzle at float4 granularity: spreads the 32B-strided window reads
// across banks (worst case 2-way = free). Bijective within 1KB groups.
__device__ __forceinline__ int swz(int f4) { return f4 ^ ((f4 >> 3) & 7); }

__device__ __forceinline__ fx4 ntload4(const float* p) {
  return __builtin_nontemporal_load((const fx4*)p);
}

// 128-thr blocks, 4 waves/SIMD (VGPR<=128): 8 blocks/CU co-resident.
__global__ __launch_bounds__(BLOCK, 4) void talos_main(
    const float* __restrict__ y_pred,
    const float* __restrict__ y_true,
    const float* __restrict__ theta,
    const int* __restrict__ pidx,
    float* __restrict__ partial) {

  __shared__ float tile[TILE_F4 * 4];          // 4224 B, swizzled
  __shared__ float wsh[S_N];
  __shared__ float redL[BLOCK / 64];

  const int bid   = blockIdx.x;
  const int b     = bid >> 4;                  // bid / NCHUNK
  const int chunk = bid & (NCHUNK - 1);
  const int t0    = chunk * TCHUNK;
  const int tid   = threadIdx.x;
  const float* yt_b = y_true + b * T_LEN;
  const float* yp_b = y_pred + b * T_LEN;

  // ---- issue theta load first: latency hides under tile staging ----
  float thv = -1e30f;
  if (tid < S_N) thv = theta[pidx[b] * S_N + tid];

  // ---- yp loads issued early (independent of LDS); nontemporal: no reuse ----
  const int lt0 = tid * VT;
  float yp[VT];
  *(fx4*)&yp[0] = ntload4(yp_b + t0 + lt0);
  *(fx4*)&yp[4] = ntload4(yp_b + t0 + lt0 + 4);

  // ---- stage y_true chunk + halo into swizzled LDS (float4, zero-padded) ----
  // Two full passes + 8-thread remainder (TILE_F4 = 264 = 2*128 + 8).
  {
    int f = tid;                               // pass 0: f in [0,128)
    int g = t0 - HALO + f * 4;
    fx4 v;
    if (g >= 0 && g + 3 < T_LEN) {
      v = ntload4(yt_b + g);
    } else {
      v.x = (g + 0 >= 0 && g + 0 < T_LEN) ? yt_b[g + 0] : 0.f;
      v.y = (g + 1 >= 0 && g + 1 < T_LEN) ? yt_b[g + 1] : 0.f;
      v.z = (g + 2 >= 0 && g + 2 < T_LEN) ? yt_b[g + 2] : 0.f;
      v.w = (g + 3 >= 0 && g + 3 < T_LEN) ? yt_b[g + 3] : 0.f;
    }
    *(fx4*)&tile[swz(f) * 4] = v;

    f = tid + BLOCK;                           // pass 1: f in [128,256) — interior
    g = t0 - HALO + f * 4;
    v = ntload4(yt_b + g);
    *(fx4*)&tile[swz(f) * 4] = v;

    if (tid < TILE_F4 - 2 * BLOCK) {           // remainder: f in [256,264)
      f = tid + 2 * BLOCK;
      g = t0 - HALO + f * 4;
      if (g + 3 < T_LEN) {
        v = ntload4(yt_b + g);
      } else {
        v.x = (g + 0 < T_LEN) ? yt_b[g + 0] : 0.f;
        v.y = (g + 1 < T_LEN) ? yt_b[g + 1] : 0.f;
        v.z = (g + 2 < T_LEN) ? yt_b[g + 2] : 0.f;
        v.w = (g + 3 < T_LEN) ? yt_b[g + 3] : 0.f;
      }
      *(fx4*)&tile[swz(f) * 4] = v;
    }
  }

  // ---- softmax weights for this b (wave 0, lanes 0..31) ----
  if (tid < 32) {
    float m = thv;
#pragma unroll
    for (int off = 16; off; off >>= 1) m = fmaxf(m, __shfl_xor(m, off, 32));
    float e = (tid < S_N) ? __expf(thv - m) : 0.f;
    float s = e;
#pragma unroll
    for (int off = 16; off; off >>= 1) s += __shfl_xor(s, off, 32);
    if (tid < S_N) wsh[tid] = e / s;
  }
  __syncthreads();

  // ---- register-blocked weighted 31-tap convolution over VT=8 elements ----
  float win[VT + 2 * HALO];                    // 40 floats: yt[t0+lt0-16 .. +23]
#pragma unroll
  for (int q = 0; q < (VT + 2 * HALO) / 4; ++q) {
    int f4 = (lt0 >> 2) + q;                   // 2*tid + q
    *(fx4*)&win[q * 4] = *(const fx4*)&tile[swz(f4) * 4];
  }

  float lin[VT];
#pragma unroll
  for (int j = 0; j < VT; ++j) lin[j] = 0.f;
#pragma unroll
  for (int s = 0; s < S_N; ++s) {
    const float ws = wsh[s];                   // LDS broadcast (no conflict)
#pragma unroll
    for (int j = 0; j < VT; ++j)
      lin[j] = fmaf(ws, win[j + s + 1], lin[j]);   // lin[t] = sum_s w_s*yt[t+s-15]
  }

  // acc = sum (yp^2 - 2*yp*lin) + sum yt^2   (weighted yt^2 collapses to the
  // unweighted per-chunk sum since sum_s w_s = 1; edges corrected below)
  float acc = 0.f;
#pragma unroll
  for (int j = 0; j < VT; ++j) {
    acc = fmaf(yp[j], fmaf(-2.f, lin[j], yp[j]), acc);
    float a = win[HALO + j];
    acc = fmaf(a, a, acc);
  }

  // ---- zero-pad edge corrections, wave-parallel (verified absmax=0, R4-R9) ----
  if (chunk == 0 && tid < M_SH) {
    float a = yt_b[tid];
    float tw = 0.f;
#pragma unroll
    for (int k = 1; k <= M_SH; ++k) if (k > tid) tw += wsh[k + M_SH];
    acc -= a * a * tw;
  }
  if (chunk == NCHUNK - 1 && tid < M_SH) {
    const int j = tid + 1;
    float z = yt_b[T_LEN - j];
    float tw = 0.f;
#pragma unroll
    for (int k = 1; k <= M_SH; ++k) if (k >= j) tw += wsh[M_SH - k];
    acc -= z * z * tw;
  }

  // ---- block reduce -> partial[bid] (plain store; kernel boundary = release) ----
#pragma unroll
  for (int off = 32; off; off >>= 1) acc += __shfl_down(acc, off, 64);
  const int lane = tid & 63, wv = tid >> 6;
  if (lane == 0) redL[wv] = acc;
  __syncthreads();
  if (tid == 0) {
    float P = 0.f;
#pragma unroll
    for (int i = 0; i < BLOCK / 64; ++i) P += redL[i];
    partial[bid] = P;
  }
}

// Minimal tail: ONE wave (64 threads), 32 partials/thread as 8x float4,
// in-register + shuffle reduce only — no LDS, no __syncthreads.
__global__ __launch_bounds__(64) void talos_tail(
    const float* __restrict__ partial, float* __restrict__ out) {
  const int tid = threadIdx.x;                 // 0..63
  double a = 0.0;
#pragma unroll
  for (int q = 0; q < NBLOCKS / 4 / 64; ++q) {  // 8 iterations
    fx4 v = *(const fx4*)(partial + (q * 64 + tid) * 4);
    a += (double)v.x + (double)v.y + (double)v.z + (double)v.w;
  }
#pragma unroll
  for (int off = 32; off; off >>= 1) a += __shfl_down(a, off, 64);
  if (tid == 0)
    out[0] = (float)(a / ((double)T_LEN * (double)B_N));
}

extern "C" void kernel_launch(void* const* d_in, const int* in_sizes, int n_in,
                              void* d_out, int out_size, void* d_ws, size_t ws_size,
                              hipStream_t stream) {
  const float* y_pred = (const float*)d_in[0];
  const float* y_true = (const float*)d_in[1];
  const float* theta  = (const float*)d_in[2];
  const int*   pidx   = (const int*)d_in[3];
  float* out = (float*)d_out;
  float* partial = (float*)d_ws;               // 2048 floats

  talos_main<<<NBLOCKS, BLOCK, 0, stream>>>(y_pred, y_true, theta, pidx, partial);
  talos_tail<<<1, 64, 0, stream>>>(partial, out);
}